// Round 1
// baseline (66.309 us; speedup 1.0000x reference)
//
#include <hip/hip_runtime.h>
#include <math.h>

// VariationalQuantumAttention — reduced form.
//
// Derivation (exact algebra, not an approximation):
//  - Query and key registers are a product state until the interaction block.
//  - Interaction: CRY(ctrl=query_i, tgt=key_i) never mixes query basis
//    states; CRZ(ctrl=key_i, tgt=query_i) is diagonal. Hence for each query
//    basis state x, the key block evolves by a unitary M_x plus phases.
//  - Output P(q0=0, q1=0) = sum_{x: x0=x1=0} |psi_q[x]|^2 * ||M_x psi_k||^2
//    and ||M_x psi_k|| = ||psi_k|| = 1. Key register and W_int cancel exactly.
//
// So: simulate only the 4-qubit query circuit (16 complex amps, in regs).
// Wire w -> bit position (3 - w) in the flattened index (wire 0 = MSB).

__global__ __launch_bounds__(64) void vqa_query_kernel(
    const float* __restrict__ query,   // [B][64], only first 4 cols used
    const float* __restrict__ Wqy,     // [2][4]
    const float* __restrict__ Wqz,     // [2][4]
    float* __restrict__ out,           // [B]
    int B)
{
    const int b = blockIdx.x * blockDim.x + threadIdx.x;
    if (b >= B) return;

    // One float4 load per row: coalesced 16 B / thread.
    const float4 qv = *reinterpret_cast<const float4*>(query + (size_t)b * 64);
    float qf[4];
    qf[0] = tanhf(qv.x);
    qf[1] = tanhf(qv.y);
    qf[2] = tanhf(qv.z);
    qf[3] = tanhf(qv.w);

    // 16 complex amplitudes, fully unrolled -> registers.
    float sr[16], si[16];
#pragma unroll
    for (int j = 0; j < 16; ++j) { sr[j] = 0.0f; si[j] = 0.0f; }
    sr[0] = 1.0f;

    const float PI = 3.14159265358979323846f;

#pragma unroll
    for (int layer = 0; layer < 2; ++layer) {
#pragma unroll
        for (int i = 0; i < 4; ++i) {
            const int str = 1 << (3 - i);   // bit position of wire i

            // RY(q_i*pi) then RY(W_q_y) == RY(q_i*pi + W_q_y); matrix uses
            // half-angle: [[c,-s],[s,c]] with c=cos(t/2), s=sin(t/2).
            const float half = 0.5f * (qf[i] * PI + Wqy[layer * 4 + i]);
            float c, s;
            __sincosf(half, &s, &c);
#pragma unroll
            for (int base = 0; base < 16; ++base) {
                if (base & str) continue;
                const int j0 = base, j1 = base | str;
                const float a0r = sr[j0], a0i = si[j0];
                const float a1r = sr[j1], a1i = si[j1];
                sr[j0] = c * a0r - s * a1r;  si[j0] = c * a0i - s * a1i;
                sr[j1] = s * a0r + c * a1r;  si[j1] = s * a0i + c * a1i;
            }

            // RZ(t): bit=0 amp *= e^{-i t/2}; bit=1 amp *= e^{+i t/2}.
            const float hz = 0.5f * Wqz[layer * 4 + i];
            float cz, sz;
            __sincosf(hz, &sz, &cz);
#pragma unroll
            for (int j = 0; j < 16; ++j) {
                const float ar = sr[j], ai = si[j];
                if (j & str) { sr[j] = ar * cz - ai * sz; si[j] = ai * cz + ar * sz; }
                else         { sr[j] = ar * cz + ai * sz; si[j] = ai * cz - ar * sz; }
            }
        }

        // CNOT chain: control wire i (bit 3-i), target wire i+1 (bit 2-i):
        // swap amps where control bit = 1, over target bit. Pure register
        // permutation after unrolling.
#pragma unroll
        for (int i = 0; i < 3; ++i) {
            const int cb = 1 << (3 - i);
            const int tb = 1 << (2 - i);
#pragma unroll
            for (int j = 0; j < 16; ++j) {
                if ((j & cb) && !(j & tb)) {
                    const int j2 = j | tb;
                    float t;
                    t = sr[j]; sr[j] = sr[j2]; sr[j2] = t;
                    t = si[j]; si[j] = si[j2]; si[j2] = t;
                }
            }
        }
    }

    // P(wire0=0 & wire1=0): top two bits zero -> indices 0..3.
    float p00 = 0.0f;
#pragma unroll
    for (int j = 0; j < 4; ++j) p00 += sr[j] * sr[j] + si[j] * si[j];
    out[b] = p00;
}

extern "C" void kernel_launch(void* const* d_in, const int* in_sizes, int n_in,
                              void* d_out, int out_size, void* d_ws, size_t ws_size,
                              hipStream_t stream) {
    const float* query = (const float*)d_in[0];
    // d_in[1] = key      (unused — proven irrelevant)
    const float* Wqy   = (const float*)d_in[2];
    const float* Wqz   = (const float*)d_in[3];
    // d_in[4] = W_k_y, d_in[5] = W_k_z, d_in[6] = W_int (all unused)
    float* out = (float*)d_out;

    const int B = in_sizes[0] / 64;   // feature dim D = 64 per reference

    const int block = 64;
    const int grid = (B + block - 1) / block;
    vqa_query_kernel<<<grid, block, 0, stream>>>(query, Wqy, Wqz, out, B);
}

// Round 2
// 65.587 us; speedup vs baseline: 1.0110x; 1.0110x over previous
//
#include <hip/hip_runtime.h>
#include <math.h>

// VariationalQuantumAttention — reduced form.
//
// Derivation (exact algebra, not an approximation):
//  - Query and key registers are a product state until the interaction block.
//  - Interaction: CRY(ctrl=query_i, tgt=key_i) never mixes query basis
//    states; CRZ(ctrl=key_i, tgt=query_i) is diagonal. Hence for each query
//    basis state x, the key block evolves by a unitary M_x plus phases.
//  - Output P(q0=0, q1=0) = sum_{x: x0=x1=0} |psi_q[x]|^2 * ||M_x psi_k||^2
//    and ||M_x psi_k|| = ||psi_k|| = 1. Key register and W_int cancel exactly.
//
// So: simulate only the 4-qubit query circuit (16 complex amps, in regs).
// Wire w -> bit position (3 - w) in the flattened index (wire 0 = MSB).

// tanh via exp: tanh(x) = 1 - 2/(e^{2x}+1). v_exp_f32 + v_rcp_f32, no libm
// call. Monotone, saturates correctly for |x| large (e^{2x} -> inf or 0).
__device__ __forceinline__ float fast_tanh(float x) {
    const float e = __expf(2.0f * x);
    return 1.0f - 2.0f / (e + 1.0f);
}

__global__ __launch_bounds__(256) void vqa_query_kernel(
    const float* __restrict__ query,   // [B][64], only first 4 cols used
    const float* __restrict__ Wqy,     // [2][4]
    const float* __restrict__ Wqz,     // [2][4]
    float* __restrict__ out,           // [B]
    int B)
{
    const int b = blockIdx.x * blockDim.x + threadIdx.x;
    if (b >= B) return;

    // One float4 load per row (stride 256 B between lanes; total 128 KB).
    const float4 qv = *reinterpret_cast<const float4*>(query + (size_t)b * 64);
    float qf[4];
    qf[0] = fast_tanh(qv.x);
    qf[1] = fast_tanh(qv.y);
    qf[2] = fast_tanh(qv.z);
    qf[3] = fast_tanh(qv.w);

    // 16 complex amplitudes, fully unrolled -> registers.
    float sr[16], si[16];
#pragma unroll
    for (int j = 0; j < 16; ++j) { sr[j] = 0.0f; si[j] = 0.0f; }
    sr[0] = 1.0f;

    const float PI = 3.14159265358979323846f;

#pragma unroll
    for (int layer = 0; layer < 2; ++layer) {
#pragma unroll
        for (int i = 0; i < 4; ++i) {
            const int str = 1 << (3 - i);   // bit position of wire i

            // RY(q_i*pi) then RY(W_q_y) == RY(q_i*pi + W_q_y); matrix uses
            // half-angle: [[c,-s],[s,c]] with c=cos(t/2), s=sin(t/2).
            const float half = 0.5f * (qf[i] * PI + Wqy[layer * 4 + i]);
            float c, s;
            __sincosf(half, &s, &c);
#pragma unroll
            for (int base = 0; base < 16; ++base) {
                if (base & str) continue;
                const int j0 = base, j1 = base | str;
                const float a0r = sr[j0], a0i = si[j0];
                const float a1r = sr[j1], a1i = si[j1];
                sr[j0] = c * a0r - s * a1r;  si[j0] = c * a0i - s * a1i;
                sr[j1] = s * a0r + c * a1r;  si[j1] = s * a0i + c * a1i;
            }

            // RZ(t): bit=0 amp *= e^{-i t/2}; bit=1 amp *= e^{+i t/2}.
            const float hz = 0.5f * Wqz[layer * 4 + i];
            float cz, sz;
            __sincosf(hz, &sz, &cz);
#pragma unroll
            for (int j = 0; j < 16; ++j) {
                const float ar = sr[j], ai = si[j];
                if (j & str) { sr[j] = ar * cz - ai * sz; si[j] = ai * cz + ar * sz; }
                else         { sr[j] = ar * cz + ai * sz; si[j] = ai * cz - ar * sz; }
            }
        }

        // CNOT chain: control wire i (bit 3-i), target wire i+1 (bit 2-i):
        // swap amps where control bit = 1 over the target bit — a pure
        // register permutation once unrolled.
#pragma unroll
        for (int i = 0; i < 3; ++i) {
            const int cb = 1 << (3 - i);
            const int tb = 1 << (2 - i);
#pragma unroll
            for (int j = 0; j < 16; ++j) {
                if ((j & cb) && !(j & tb)) {
                    const int j2 = j | tb;
                    float t;
                    t = sr[j]; sr[j] = sr[j2]; sr[j2] = t;
                    t = si[j]; si[j] = si[j2]; si[j2] = t;
                }
            }
        }
    }

    // P(wire0=0 & wire1=0): top two bits zero -> indices 0..3.
    float p00 = 0.0f;
#pragma unroll
    for (int j = 0; j < 4; ++j) p00 += sr[j] * sr[j] + si[j] * si[j];
    out[b] = p00;
}

extern "C" void kernel_launch(void* const* d_in, const int* in_sizes, int n_in,
                              void* d_out, int out_size, void* d_ws, size_t ws_size,
                              hipStream_t stream) {
    const float* query = (const float*)d_in[0];
    // d_in[1] = key      (unused — proven irrelevant)
    const float* Wqy   = (const float*)d_in[2];
    const float* Wqz   = (const float*)d_in[3];
    // d_in[4] = W_k_y, d_in[5] = W_k_z, d_in[6] = W_int (all unused)
    float* out = (float*)d_out;

    const int B = in_sizes[0] / 64;   // feature dim D = 64 per reference

    const int block = 256;
    const int grid = (B + block - 1) / block;
    vqa_query_kernel<<<grid, block, 0, stream>>>(query, Wqy, Wqz, out, B);
}